// Round 7
// baseline (53.063 us; speedup 1.0000x reference)
//
#include <hip/hip_runtime.h>

// Spiking eLIF layer: x (B=64, C=512, T=1024) f32, beta scalar, vth (C,).
//   rst = spk*vth; mem = mem*beta + x[t] - rst; spk = (mem > vth) ? 1 : 0
// Output spk, layout (B, C, T).
//
// Structure (R6, kept): 1 wave per block = 64 consecutive rows; slab = 64
// t-steps; global access fully coalesced via LDS transpose with XOR swizzle
// (pcol = j ^ (row&15)) applied by PRE-SWIZZLING the global address; LDS
// writes/reads are bank-conflict-free (measured 0 in R6).
//
// New (R7): prefetch depth 2 via global_load_lds DMA (no staging registers,
// compiler cannot re-sink it — R4/R5 showed register prefetch gets collapsed)
// with hand-counted s_waitcnt vmcnt(N). 3 LDS in-buffers. Invariant: exactly
// 32 VMEM ops (16 loads + 16 stores) issue between slab ch's loads and
// iteration ch's wait => vmcnt(32) guarantees slab ch is in LDS, while
// leaving the next 2 slabs' loads in flight (16 MB aggregate, Little's law
// satisfied for ~6 TB/s). First iteration peeled with vmcnt(16).
// Single wave per block => no __syncthreads => no vmcnt(0) drain anywhere.
//
// Correctness: __f*_rn forbids FMA contraction (bit-exact vs numpy fp32; one
// flipped spike corrupts the rest of the row via the reset term).
// (mem > vth) == (fl(mem - vth) > 0) in IEEE RN with gradual underflow.

typedef float f32x4 __attribute__((ext_vector_type(4)));

#define T_LEN 1024
#define C_LEN 512
#define RPB   64                 // rows per block (= lanes per wave)
#define VECS  16                 // f32x4 per row per slab (64 floats)
#define NCH   (T_LEN / (VECS * 4)) // 16 slabs
#define ROWV  (T_LEN / 4)        // row stride in f32x4 = 256

#define GLL(g_, l_)                                                     \
    __builtin_amdgcn_global_load_lds(                                   \
        (const __attribute__((address_space(1))) void*)(g_),            \
        (__attribute__((address_space(3))) void*)(l_), 16, 0, 0)

#define WAITV(n_) asm volatile("s_waitcnt vmcnt(" #n_ ")" ::: "memory")

#define STEP(xv_, sv_)                                 \
    do {                                               \
        float m1_ = __fmul_rn(mem, beta);              \
        float m2_ = __fadd_rn(m1_, (xv_));             \
        mem = __fsub_rn(m2_, rst);                     \
        bool b_ = (mem > vth);                         \
        (sv_) = b_ ? 1.0f : 0.0f;                      \
        rst = b_ ? vth : 0.0f;                         \
    } while (0)

// 16 DMA loads for slab ch into in_lds[buf]. Global source is per-lane,
// pre-swizzled (instr j covers rows 4j..4j+3, 16 contiguous lanes per row,
// col = c16 ^ (row&15)). LDS dest is the wave-uniform base &in_lds[buf][64j];
// HW writes base + lane*16 == slot 64j + l.
#define LOADS(buf, ch)                                                        \
    do {                                                                      \
        _Pragma("unroll")                                                     \
        for (int j_ = 0; j_ < VECS; ++j_) {                                   \
            const int rj_ = 4 * j_ + l4;                                      \
            const int gc_ = c16 ^ (rj_ & 15);                                 \
            GLL(xv + (size_t)(rb + rj_) * ROWV + (ch) * VECS + gc_,           \
                &in_lds[buf][64 * j_]);                                       \
        }                                                                     \
    } while (0)

// lane l scans its own row l: logical col j at physical slot l*16 + (j^c16)
#define COMPUTE(buf)                                                      \
    do {                                                                  \
        _Pragma("unroll")                                                 \
        for (int j_ = 0; j_ < VECS; ++j_) {                               \
            f32x4 v_ = in_lds[buf][l * VECS + (j_ ^ c16)];                \
            f32x4 s_;                                                     \
            STEP(v_.x, s_.x);                                             \
            STEP(v_.y, s_.y);                                             \
            STEP(v_.z, s_.z);                                             \
            STEP(v_.w, s_.w);                                             \
            out_lds[l * VECS + (j_ ^ c16)] = s_;                          \
        }                                                                 \
    } while (0)

// mirror of LOADS: lane-linear LDS read, coalesced (pre-swizzled) store
#define DRAIN(ch)                                                         \
    do {                                                                  \
        _Pragma("unroll")                                                 \
        for (int j_ = 0; j_ < VECS; ++j_) {                               \
            const int rj_ = 4 * j_ + l4;                                  \
            const int gc_ = c16 ^ (rj_ & 15);                             \
            ov[(size_t)(rb + rj_) * ROWV + (ch) * VECS + gc_] =           \
                out_lds[64 * j_ + l];                                     \
        }                                                                 \
    } while (0)

__global__ __launch_bounds__(64, 1) void elif_scan_kernel(
    const float* __restrict__ x,
    const float* __restrict__ beta_p,
    const float* __restrict__ vth_p,
    float* __restrict__ out)
{
    __shared__ f32x4 in_lds[3][RPB * VECS];   // 3 x 16 KB
    __shared__ f32x4 out_lds[RPB * VECS];     // 16 KB

    const int l   = threadIdx.x;   // lane 0..63
    const int l4  = l >> 4;        // 0..3
    const int c16 = l & 15;        // 0..15
    const int rb  = blockIdx.x * RPB;

    const f32x4* __restrict__ xv = (const f32x4*)x;
    f32x4* __restrict__       ov = (f32x4*)out;

    const float beta = beta_p[0];
    const float vth  = vth_p[(rb + l) & (C_LEN - 1)];

    float mem = 0.0f;
    float rst = 0.0f;

    // prologue: slabs 0 and 1 in flight
    LOADS(0, 0);
    LOADS(1, 1);

    // peeled ch=0: only L(1) (16 ops) issued after L(0) -> vmcnt(16)
    WAITV(16);
    COMPUTE(0);
    LOADS(2, 2);
    DRAIN(0);

    // steady state: exactly 32 VMEM ops (L(ch+1) 16 + S(ch-1) 16) issued
    // after slab ch's loads -> vmcnt(32) proves slab ch landed in LDS.
    #pragma unroll 1
    for (int ch = 1; ch < NCH; ++ch) {
        WAITV(32);
        COMPUTE(ch % 3);
        if (ch + 2 < NCH) LOADS((ch + 2) % 3, ch + 2);
        DRAIN(ch);
    }
}

extern "C" void kernel_launch(void* const* d_in, const int* in_sizes, int n_in,
                              void* d_out, int out_size, void* d_ws, size_t ws_size,
                              hipStream_t stream) {
    const float* x      = (const float*)d_in[0];
    const float* beta_p = (const float*)d_in[1];
    const float* vth_p  = (const float*)d_in[2];
    float* out          = (float*)d_out;

    const int n_rows = in_sizes[0] / T_LEN;      // B*C = 32768
    const int grid   = n_rows / RPB;             // 512 blocks -> 2 per CU

    elif_scan_kernel<<<grid, RPB, 0, stream>>>(x, beta_p, vth_p, out);
}

// Round 8
// 50.360 us; speedup vs baseline: 1.0537x; 1.0537x over previous
//
#include <hip/hip_runtime.h>

// Spiking eLIF layer: x (B=64, C=512, T=1024) f32, beta scalar, vth (C,).
//   rst = spk*vth; mem = mem*beta + x[t] - rst; spk = (mem > vth) ? 1 : 0
// Output spk, layout (B, C, T).
//
// Structure (R6/R7): 1 wave per block = 64 consecutive rows (512 waves total,
// 2/CU — structural cap). Slab = 64 t-steps/row. Global access fully
// coalesced via LDS transpose; XOR swizzle (pcol = j ^ (row&15)) applied by
// PRE-SWIZZLING the global address so global_load_lds' lane-linear LDS write
// lands swizzled; per-row LDS reads bank-conflict-free (measured 0).
// Prefetch depth 2 via global_load_lds DMA + hand-counted vmcnt.
//
// R7 lesson (wait-count bug): vmcnt retires IN ORDER; with issue order
// ..., L(ch), D(ch-2), L(ch+1), D(ch-1), [WAIT], vmcnt(32) forced D(ch-2)'s
// 16 HBM stores retired every iteration -> store-ack serialization (53us).
// Fix: vmcnt(48) keeps only L(ch) (+3-iter-old stores) in the required
// window; recent stores and both prefetch slabs stay in flight.
// Peels: ch=0 ->16, ch=1 ->32, ch=2..14 ->48, ch=15 ->32 (tail issues no
// loads; 48 would under-wait: only 32 ops issue after L(15)).
//
// Correctness: __f*_rn forbids FMA contraction (bit-exact vs numpy fp32; one
// flipped spike corrupts the rest of the row via the reset term).
// (mem > vth) == (fl(mem - vth) > 0) in IEEE RN with gradual underflow.

typedef float f32x4 __attribute__((ext_vector_type(4)));

#define T_LEN 1024
#define C_LEN 512
#define RPB   64                   // rows per block (= lanes per wave)
#define VECS  16                   // f32x4 per row per slab (64 floats)
#define NCH   (T_LEN / (VECS * 4)) // 16 slabs
#define ROWV  (T_LEN / 4)          // row stride in f32x4 = 256

#define GLL(g_, l_)                                                     \
    __builtin_amdgcn_global_load_lds(                                   \
        (const __attribute__((address_space(1))) void*)(g_),            \
        (__attribute__((address_space(3))) void*)(l_), 16, 0, 0)

#define WAITV(n_) asm volatile("s_waitcnt vmcnt(" #n_ ")" ::: "memory")

#define STEP(xv_, sv_)                                 \
    do {                                               \
        float m1_ = __fmul_rn(mem, beta);              \
        float m2_ = __fadd_rn(m1_, (xv_));             \
        mem = __fsub_rn(m2_, rst);                     \
        bool b_ = (mem > vth);                         \
        (sv_) = b_ ? 1.0f : 0.0f;                      \
        rst = b_ ? vth : 0.0f;                         \
    } while (0)

// 16 DMA loads for slab ch into in_lds[buf]. Global source per-lane,
// pre-swizzled (instr j covers rows 4j..4j+3, 16 contiguous lanes per row,
// col = c16 ^ (row&15)). LDS dest = wave-uniform base &in_lds[buf][64j];
// HW writes base + lane*16 == slot 64j + l.
#define LOADS(buf, ch)                                                        \
    do {                                                                      \
        _Pragma("unroll")                                                     \
        for (int j_ = 0; j_ < VECS; ++j_) {                                   \
            const int rj_ = 4 * j_ + l4;                                      \
            const int gc_ = c16 ^ (rj_ & 15);                                 \
            GLL(xv + (size_t)(rb + rj_) * ROWV + (ch) * VECS + gc_,           \
                &in_lds[buf][64 * j_]);                                       \
        }                                                                     \
    } while (0)

// lane l scans its own row l: logical col j at physical slot l*16 + (j^c16)
#define COMPUTE(buf)                                                      \
    do {                                                                  \
        _Pragma("unroll")                                                 \
        for (int j_ = 0; j_ < VECS; ++j_) {                               \
            f32x4 v_ = in_lds[buf][l * VECS + (j_ ^ c16)];                \
            f32x4 s_;                                                     \
            STEP(v_.x, s_.x);                                             \
            STEP(v_.y, s_.y);                                             \
            STEP(v_.z, s_.z);                                             \
            STEP(v_.w, s_.w);                                             \
            out_lds[l * VECS + (j_ ^ c16)] = s_;                          \
        }                                                                 \
    } while (0)

// mirror of LOADS: lane-linear LDS read, coalesced (pre-swizzled) store
#define DRAIN(ch)                                                         \
    do {                                                                  \
        _Pragma("unroll")                                                 \
        for (int j_ = 0; j_ < VECS; ++j_) {                               \
            const int rj_ = 4 * j_ + l4;                                  \
            const int gc_ = c16 ^ (rj_ & 15);                             \
            ov[(size_t)(rb + rj_) * ROWV + (ch) * VECS + gc_] =           \
                out_lds[64 * j_ + l];                                     \
        }                                                                 \
    } while (0)

__global__ __launch_bounds__(64, 1) void elif_scan_kernel(
    const float* __restrict__ x,
    const float* __restrict__ beta_p,
    const float* __restrict__ vth_p,
    float* __restrict__ out)
{
    __shared__ f32x4 in_lds[3][RPB * VECS];   // 3 x 16 KB
    __shared__ f32x4 out_lds[RPB * VECS];     // 16 KB

    const int l   = threadIdx.x;   // lane 0..63
    const int l4  = l >> 4;        // 0..3
    const int c16 = l & 15;        // 0..15
    const int rb  = blockIdx.x * RPB;

    const f32x4* __restrict__ xv = (const f32x4*)x;
    f32x4* __restrict__       ov = (f32x4*)out;

    const float beta = beta_p[0];
    const float vth  = vth_p[(rb + l) & (C_LEN - 1)];

    float mem = 0.0f;
    float rst = 0.0f;

    // prologue: slabs 0 and 1 in flight
    LOADS(0, 0);
    LOADS(1, 1);

    // ch=0: 16 ops (L1) issued after L0 -> vmcnt(16) retires exactly L0.
    WAITV(16);
    COMPUTE(0);
    LOADS(2, 2);
    DRAIN(0);

    // ch=1: after L1: L2(16) + D0(16) -> vmcnt(32) retires L0,L1 only.
    WAITV(32);
    COMPUTE(1);
    LOADS(0, 3);
    DRAIN(1);

    // steady state ch=2..14: after L(ch): D(ch-2),L(ch+1),D(ch-1) = 48 ops
    // -> vmcnt(48) retires L(ch) (+stores >=3 iters old), never recent stores.
    #pragma unroll 1
    for (int ch = 2; ch < NCH - 1; ++ch) {
        WAITV(48);
        COMPUTE(ch % 3);
        if (ch + 2 < NCH) LOADS((ch + 2) % 3, ch + 2);
        DRAIN(ch);
    }

    // ch=15: only D(13),D(14) = 32 ops issued after L(15) -> vmcnt(32).
    WAITV(32);
    COMPUTE(15 % 3);
    DRAIN(15);
}

extern "C" void kernel_launch(void* const* d_in, const int* in_sizes, int n_in,
                              void* d_out, int out_size, void* d_ws, size_t ws_size,
                              hipStream_t stream) {
    const float* x      = (const float*)d_in[0];
    const float* beta_p = (const float*)d_in[1];
    const float* vth_p  = (const float*)d_in[2];
    float* out          = (float*)d_out;

    const int n_rows = in_sizes[0] / T_LEN;      // B*C = 32768
    const int grid   = n_rows / RPB;             // 512 blocks -> 2 per CU

    elif_scan_kernel<<<grid, RPB, 0, stream>>>(x, beta_p, vth_p, out);
}

// Round 9
// 47.989 us; speedup vs baseline: 1.1057x; 1.0494x over previous
//
#include <hip/hip_runtime.h>

// Spiking eLIF layer: x (B=64, C=512, T=1024) f32, beta scalar, vth (C,).
//   rst = spk*vth; mem = mem*beta + x[t] - rst; spk = (mem > vth) ? 1 : 0
// Output spk, layout (B, C, T).
//
// R9: R6's winning register-staged LDS-transpose structure, with ROWS=32
// rows per wave (was 64) -> 1024 blocks -> 4 waves/CU (was 2). R7/R8 showed
// deeper VMEM prefetch (DMA + counted vmcnt) loses to this structure; the
// residual gap vs the ~42us write-path floor (131MB at ~3.15 TB/s write) is
// latency bubbles, attacked here via TLP (more streams/CU), the one lever
// left at a structural 1-thread-per-row occupancy cap.
//  - global access fully coalesced: load instr j covers 4 rows x 256B
//    contiguous segments (16 contiguous lanes per row).
//  - XOR swizzle (pcol = j ^ (row&15)) applied by pre-swizzling the GLOBAL
//    address; LDS writes lane-linear, per-row LDS reads bank-conflict-free
//    (measured 0 in R6/R7/R8).
//  - COMPUTE is exec-masked to lanes 0..31 (one lane per row); VALU issue
//    doubles chip-wide (~17us/CU) but stays far under the write floor.
//  - single wave per block => no __syncthreads, no vmcnt(0) drains; the
//    compiler schedules per-register vmcnt for the staged loads (this beat
//    both sched_barrier pinning and global_load_lds DMA empirically).
//
// Correctness: __f*_rn forbids FMA contraction (bit-exact vs numpy fp32; one
// flipped spike corrupts the rest of the row via the reset term).
// (mem > vth) == (fl(mem - vth) > 0) in IEEE RN with gradual underflow.

typedef float f32x4 __attribute__((ext_vector_type(4)));

#define T_LEN 1024
#define C_LEN 512
#define ROWS  32                   // rows per wave/block
#define VECS  16                   // f32x4 per row per slab (64 floats)
#define NCH   (T_LEN / (VECS * 4)) // 16 slabs
#define ROWV  (T_LEN / 4)          // row stride in f32x4 = 256
#define NLD   (ROWS / 4)           // load/store instrs per slab = 8

#define STEP(xv_, sv_)                                 \
    do {                                               \
        float m1_ = __fmul_rn(mem, beta);              \
        float m2_ = __fadd_rn(m1_, (xv_));             \
        mem = __fsub_rn(m2_, rst);                     \
        bool b_ = (mem > vth);                         \
        (sv_) = b_ ? 1.0f : 0.0f;                      \
        rst = b_ ? vth : 0.0f;                         \
    } while (0)

// 8 coalesced loads: instr j covers rows 4j..4j+3, 16 contiguous lanes per
// row; global col pre-swizzled so the LDS write below is lane-linear.
#define LOADS(ch)                                                         \
    do {                                                                  \
        _Pragma("unroll")                                                 \
        for (int j_ = 0; j_ < NLD; ++j_) {                                \
            const int rj_ = 4 * j_ + l4;                                  \
            const int gc_ = c16 ^ (rj_ & 15);                             \
            stg[j_] = xv[(size_t)(rb + rj_) * ROWV + (ch) * VECS + gc_];  \
        }                                                                 \
    } while (0)

// lane-linear LDS write: slot 64j + l == [row 4j+l4][pcol c16]
#define DSW(buf)                                                          \
    do {                                                                  \
        _Pragma("unroll")                                                 \
        for (int j_ = 0; j_ < NLD; ++j_)                                  \
            in_lds[buf][64 * j_ + l] = stg[j_];                           \
    } while (0)

// lane l (<32) scans row l: logical col j at physical slot l*16 + (j^c16)
#define COMPUTE(buf)                                                      \
    do {                                                                  \
        if (l < ROWS) {                                                   \
            _Pragma("unroll")                                             \
            for (int j_ = 0; j_ < VECS; ++j_) {                           \
                f32x4 v_ = in_lds[buf][l * VECS + (j_ ^ c16)];            \
                f32x4 s_;                                                 \
                STEP(v_.x, s_.x);                                         \
                STEP(v_.y, s_.y);                                         \
                STEP(v_.z, s_.z);                                         \
                STEP(v_.w, s_.w);                                         \
                out_lds[l * VECS + (j_ ^ c16)] = s_;                      \
            }                                                             \
        }                                                                 \
    } while (0)

// mirror of LOADS: lane-linear LDS read, coalesced (pre-swizzled) store
#define DRAIN(ch)                                                         \
    do {                                                                  \
        _Pragma("unroll")                                                 \
        for (int j_ = 0; j_ < NLD; ++j_) {                                \
            const int rj_ = 4 * j_ + l4;                                  \
            const int gc_ = c16 ^ (rj_ & 15);                             \
            ov[(size_t)(rb + rj_) * ROWV + (ch) * VECS + gc_] =           \
                out_lds[64 * j_ + l];                                     \
        }                                                                 \
    } while (0)

__global__ __launch_bounds__(64, 1) void elif_scan_kernel(
    const float* __restrict__ x,
    const float* __restrict__ beta_p,
    const float* __restrict__ vth_p,
    float* __restrict__ out)
{
    __shared__ f32x4 in_lds[2][ROWS * VECS];  // 2 x 8 KB
    __shared__ f32x4 out_lds[ROWS * VECS];    // 8 KB

    const int l   = threadIdx.x;   // lane 0..63
    const int l4  = l >> 4;        // 0..3
    const int c16 = l & 15;        // 0..15
    const int rb  = blockIdx.x * ROWS;

    const f32x4* __restrict__ xv = (const f32x4*)x;
    f32x4* __restrict__       ov = (f32x4*)out;

    const float beta = beta_p[0];
    const float vth  = vth_p[(rb + (l & (ROWS - 1))) & (C_LEN - 1)];

    f32x4 stg[NLD];                // staged slab (compile-time indexed only)
    float mem = 0.0f;
    float rst = 0.0f;

    // prologue: slab 0 into in_lds[0]; slab 1 loads in flight
    LOADS(0);
    DSW(0);
    LOADS(1);

    #pragma unroll 1
    for (int ch = 0; ch < NCH; ++ch) {
        // invariant: in_lds[ch&1] holds slab ch; stg holds slab ch+1 (in flight)
        COMPUTE(ch & 1);
        DRAIN(ch);
        if (ch < NCH - 1) DSW((ch + 1) & 1);   // vmcnt wait hidden under compute+drain
        if (ch < NCH - 2) LOADS(ch + 2);       // issue next slab
    }
}

extern "C" void kernel_launch(void* const* d_in, const int* in_sizes, int n_in,
                              void* d_out, int out_size, void* d_ws, size_t ws_size,
                              hipStream_t stream) {
    const float* x      = (const float*)d_in[0];
    const float* beta_p = (const float*)d_in[1];
    const float* vth_p  = (const float*)d_in[2];
    float* out          = (float*)d_out;

    const int n_rows = in_sizes[0] / T_LEN;      // B*C = 32768
    const int grid   = n_rows / ROWS;            // 1024 blocks -> 4 waves/CU

    elif_scan_kernel<<<grid, 64, 0, stream>>>(x, beta_p, vth_p, out);
}